// Round 1
// baseline (314.814 us; speedup 1.0000x reference)
//
#include <hip/hip_runtime.h>

#define FH 240
#define FW 240
#define FC 64
constexpr float IMG = 960.0f;

// ---------------- ws layout (floats) ----------------
// fmT   : [240][240][64]            -> 3,686,400 floats
// g     : [64]                      -> offset 3,686,400
// hg    : [64]                      -> offset 3,686,464
// pooled: [N][192] (3 scales x 64)  -> offset 3,686,528
static constexpr int WS_FMT = 0;
static constexpr int WS_G   = 3686400;
static constexpr int WS_HG  = 3686464;
static constexpr int WS_POOL= 3686528;

// ---------- Kernel 1: transpose fm [C,H,W] -> fmT [H,W,C] ----------
__global__ __launch_bounds__(256) void k_transpose(const float* __restrict__ fm,
                                                   float* __restrict__ fmT) {
    __shared__ float tile[64][65];
    int y  = blockIdx.y;
    int x0 = blockIdx.x * 64;
    int tid = threadIdx.x;
    int lane = tid & 63;
    int wv   = tid >> 6;
    int x = x0 + lane;
    bool xin = (x < FW);
    #pragma unroll
    for (int k = 0; k < 16; ++k) {
        int c = wv + k * 4;
        tile[c][lane] = xin ? fm[c * (FH * FW) + y * FW + x] : 0.0f;
    }
    __syncthreads();
    #pragma unroll
    for (int k = 0; k < 16; ++k) {
        int idx = tid + k * 256;      // 0..4095
        int xl = idx >> 6;
        int c  = idx & 63;
        int xx = x0 + xl;
        if (xx < FW) fmT[(y * FW + xx) * 64 + c] = tile[c][xl];
    }
}

// ---------- Kernel 2: per-channel global mean ----------
__global__ __launch_bounds__(256) void k_gmean(const float* __restrict__ fm,
                                               float* __restrict__ g) {
    int c = blockIdx.x;
    const float* p = fm + c * (FH * FW);
    float s = 0.0f;
    for (int i = threadIdx.x; i < FH * FW; i += 256) s += p[i];
    __shared__ float red[256];
    red[threadIdx.x] = s;
    __syncthreads();
    for (int st = 128; st > 0; st >>= 1) {
        if (threadIdx.x < st) red[threadIdx.x] += red[threadIdx.x + st];
        __syncthreads();
    }
    if (threadIdx.x == 0) g[c] = red[0] / (float)(FH * FW);
}

// ---------- Kernel 3: hg = head(g) (single tiny block) ----------
__global__ __launch_bounds__(128) void k_headg(const float* __restrict__ g,
                                               const float* __restrict__ W1, const float* __restrict__ b1,
                                               const float* __restrict__ W2, const float* __restrict__ b2,
                                               float* __restrict__ hg) {
    __shared__ float gs[64];
    __shared__ float h1[128];
    int t = threadIdx.x;
    if (t < 64) gs[t] = g[t];
    __syncthreads();
    float acc = b1[t];
    for (int c = 0; c < 64; ++c) acc += gs[c] * W1[c * 128 + t];
    h1[t] = fmaxf(acc, 0.0f);
    __syncthreads();
    if (t < 64) {
        float a2 = b2[t];
        for (int j = 0; j < 128; ++j) a2 += h1[j] * W2[j * 64 + t];
        hg[t] = fmaxf(a2, 0.0f);
    }
}

// ---------- Kernel 4: ROI bilinear pooling, one block per box ----------
template <int S>
__device__ __forceinline__ void pool_scale(const float* __restrict__ fmT,
                                           float cx, float cy, float w2, float h2,
                                           int c, int slot, float* red,
                                           float* __restrict__ outp) {
    constexpr int NS = S * S;
    float acc = 0.0f;
    for (int s = slot; s < NS; s += 4) {
        int i = s / S;          // grid row
        int j = s - i * S;      // grid col
        float bj = (2.0f * (float)j + 1.0f) / (float)S - 1.0f;
        float bi = (2.0f * (float)i + 1.0f) / (float)S - 1.0f;
        float gx = w2 * bj + cx;
        float gy = h2 * bi + cy;
        float ix = ((gx + 1.0f) * 240.0f - 1.0f) * 0.5f;
        float iy = ((gy + 1.0f) * 240.0f - 1.0f) * 0.5f;
        float x0f = floorf(ix), y0f = floorf(iy);
        float dx = ix - x0f, dy = iy - y0f;
        int x0 = (int)x0f, y0 = (int)y0f;
        int x1 = x0 + 1,   y1 = y0 + 1;
        bool vx0 = (x0 >= 0) & (x0 < 240);
        bool vx1 = (x1 >= 0) & (x1 < 240);
        bool vy0 = (y0 >= 0) & (y0 < 240);
        bool vy1 = (y1 >= 0) & (y1 < 240);
        int x0c = min(max(x0, 0), 239), x1c = min(max(x1, 0), 239);
        int y0c = min(max(y0, 0), 239), y1c = min(max(y1, 0), 239);
        const float* row0 = fmT + (size_t)(y0c * 240) * 64;
        const float* row1 = fmT + (size_t)(y1c * 240) * 64;
        float v00 = (vx0 & vy0) ? row0[x0c * 64 + c] : 0.0f;
        float v01 = (vx1 & vy0) ? row0[x1c * 64 + c] : 0.0f;
        float v10 = (vx0 & vy1) ? row1[x0c * 64 + c] : 0.0f;
        float v11 = (vx1 & vy1) ? row1[x1c * 64 + c] : 0.0f;
        float wx0 = 1.0f - dx, wy0 = 1.0f - dy;
        acc += (v00 * wx0 + v01 * dx) * wy0 + (v10 * wx0 + v11 * dx) * dy;
    }
    red[slot * 64 + c] = acc;
    __syncthreads();
    if (slot == 0) {
        float t = red[c] + red[64 + c] + red[128 + c] + red[192 + c];
        outp[c] = t / (float)NS;
    }
    __syncthreads();
}

__global__ __launch_bounds__(256) void k_pool(const float* __restrict__ fmT,
                                              const float* __restrict__ boxes,
                                              float* __restrict__ pooled) {
    int box = blockIdx.x;
    int tid = threadIdx.x;
    int c = tid & 63, slot = tid >> 6;
    float bx1 = boxes[box * 4 + 0], by1 = boxes[box * 4 + 1];
    float bx2 = boxes[box * 4 + 2], by2 = boxes[box * 4 + 3];
    float x1n = (bx1 / IMG) * 2.0f - 1.0f;
    float y1n = (by1 / IMG) * 2.0f - 1.0f;
    float x2n = (bx2 / IMG) * 2.0f - 1.0f;
    float y2n = (by2 / IMG) * 2.0f - 1.0f;
    float cx = (x1n + x2n) * 0.5f, cy = (y1n + y2n) * 0.5f;
    float w = fmaxf(x2n - x1n, 1e-6f), h = fmaxf(y2n - y1n, 1e-6f);
    float w2 = w * 0.5f, h2 = h * 0.5f;
    __shared__ float red[4 * 64];
    float* outp = pooled + (size_t)box * 192;
    pool_scale<3 >(fmT, cx, cy, w2, h2, c, slot, red, outp);
    pool_scale<7 >(fmT, cx, cy, w2, h2, c, slot, red, outp + 64);
    pool_scale<11>(fmT, cx, cy, w2, h2, c, slot, red, outp + 128);
}

// ---------- Kernel 5: heads (3 scales) + final MLP, 8 rows per block ----------
__global__ __launch_bounds__(256) void k_mlp(const float* __restrict__ pooled,
                                             const float* __restrict__ hg,
                                             const float* __restrict__ W1, const float* __restrict__ b1,
                                             const float* __restrict__ W2, const float* __restrict__ b2,
                                             const float* __restrict__ P1, const float* __restrict__ bp1,
                                             const float* __restrict__ P2, const float* __restrict__ bp2,
                                             float* __restrict__ out, int n) {
    constexpr int NB = 8;
    __shared__ float pool_l[NB][192];
    __shared__ float catf[NB][256];
    __shared__ float h1_l[NB][128];
    __shared__ float scratch[4 * NB * 128];
    int tid = threadIdx.x;
    int box0 = blockIdx.x * NB;

    for (int idx = tid; idx < NB * 192; idx += 256) {
        int r = idx / 192, cc = idx - r * 192;
        pool_l[r][cc] = (box0 + r < n) ? pooled[(size_t)(box0 + r) * 192 + cc] : 0.0f;
    }
    for (int idx = tid; idx < NB * 64; idx += 256) {
        int r = idx >> 6, k = idx & 63;
        catf[r][192 + k] = hg[k];
    }
    __syncthreads();

    int j = tid & 127, half = tid >> 7;   // stage-1 mapping
    int k = tid & 63,  q    = tid >> 6;   // stage-2 mapping

    for (int sc = 0; sc < 3; ++sc) {
        // h1 = relu(pooled_sc @ W1 + b1)
        float acc[NB];
        #pragma unroll
        for (int r = 0; r < NB; ++r) acc[r] = 0.0f;
        for (int c = half * 32; c < half * 32 + 32; ++c) {
            float wv = W1[c * 128 + j];
            #pragma unroll
            for (int r = 0; r < NB; ++r) acc[r] += pool_l[r][sc * 64 + c] * wv;
        }
        #pragma unroll
        for (int r = 0; r < NB; ++r) scratch[(half * NB + r) * 128 + j] = acc[r];
        __syncthreads();
        if (half == 0) {
            float bb = b1[j];
            #pragma unroll
            for (int r = 0; r < NB; ++r)
                h1_l[r][j] = fmaxf(scratch[r * 128 + j] + scratch[(NB + r) * 128 + j] + bb, 0.0f);
        }
        __syncthreads();
        // h2 = relu(h1 @ W2 + b2) -> catf[:, sc*64 .. ]
        float a2[NB];
        #pragma unroll
        for (int r = 0; r < NB; ++r) a2[r] = 0.0f;
        for (int jj = q * 32; jj < q * 32 + 32; ++jj) {
            float wv = W2[jj * 64 + k];
            #pragma unroll
            for (int r = 0; r < NB; ++r) a2[r] += h1_l[r][jj] * wv;
        }
        #pragma unroll
        for (int r = 0; r < NB; ++r) scratch[(q * NB + r) * 64 + k] = a2[r];
        __syncthreads();
        if (q == 0) {
            float bb = b2[k];
            #pragma unroll
            for (int r = 0; r < NB; ++r) {
                float v = scratch[r * 64 + k] + scratch[(NB + r) * 64 + k] +
                          scratch[(2 * NB + r) * 64 + k] + scratch[(3 * NB + r) * 64 + k] + bb;
                catf[r][sc * 64 + k] = fmaxf(v, 0.0f);
            }
        }
        __syncthreads();
    }

    // hid = relu(catf @ P1 + bp1)
    float acc[NB];
    #pragma unroll
    for (int r = 0; r < NB; ++r) acc[r] = 0.0f;
    for (int c = half * 128; c < half * 128 + 128; ++c) {
        float wv = P1[c * 128 + j];
        #pragma unroll
        for (int r = 0; r < NB; ++r) acc[r] += catf[r][c] * wv;
    }
    #pragma unroll
    for (int r = 0; r < NB; ++r) scratch[(half * NB + r) * 128 + j] = acc[r];
    __syncthreads();
    if (half == 0) {
        float bb = bp1[j];
        #pragma unroll
        for (int r = 0; r < NB; ++r)
            h1_l[r][j] = fmaxf(scratch[r * 128 + j] + scratch[(NB + r) * 128 + j] + bb, 0.0f);
    }
    __syncthreads();
    // out = relu(hid @ P2 + bp2)
    float a2[NB];
    #pragma unroll
    for (int r = 0; r < NB; ++r) a2[r] = 0.0f;
    for (int jj = q * 32; jj < q * 32 + 32; ++jj) {
        float wv = P2[jj * 64 + k];
        #pragma unroll
        for (int r = 0; r < NB; ++r) a2[r] += h1_l[r][jj] * wv;
    }
    #pragma unroll
    for (int r = 0; r < NB; ++r) scratch[(q * NB + r) * 64 + k] = a2[r];
    __syncthreads();
    if (q == 0) {
        float bb = bp2[k];
        #pragma unroll
        for (int r = 0; r < NB; ++r) {
            if (box0 + r < n) {
                float v = scratch[r * 64 + k] + scratch[(NB + r) * 64 + k] +
                          scratch[(2 * NB + r) * 64 + k] + scratch[(3 * NB + r) * 64 + k] + bb;
                out[(size_t)(box0 + r) * 64 + k] = fmaxf(v, 0.0f);
            }
        }
    }
}

extern "C" void kernel_launch(void* const* d_in, const int* in_sizes, int n_in,
                              void* d_out, int out_size, void* d_ws, size_t ws_size,
                              hipStream_t stream) {
    const float* fm    = (const float*)d_in[0];
    const float* boxes = (const float*)d_in[1];
    const float* W1    = (const float*)d_in[2];
    const float* b1    = (const float*)d_in[3];
    const float* W2    = (const float*)d_in[4];
    const float* b2    = (const float*)d_in[5];
    const float* P1    = (const float*)d_in[6];
    const float* bp1   = (const float*)d_in[7];
    const float* P2    = (const float*)d_in[8];
    const float* bp2   = (const float*)d_in[9];
    float* ws = (float*)d_ws;
    float* fmT    = ws + WS_FMT;
    float* g      = ws + WS_G;
    float* hg     = ws + WS_HG;
    float* pooled = ws + WS_POOL;
    float* out = (float*)d_out;
    int n = in_sizes[1] / 4;   // 4000 boxes

    k_transpose<<<dim3(4, 240), 256, 0, stream>>>(fm, fmT);
    k_gmean<<<64, 256, 0, stream>>>(fm, g);
    k_headg<<<1, 128, 0, stream>>>(g, W1, b1, W2, b2, hg);
    k_pool<<<n, 256, 0, stream>>>(fmT, boxes, pooled);
    k_mlp<<<(n + 7) / 8, 256, 0, stream>>>(pooled, hg, W1, b1, W2, b2,
                                           P1, bp1, P2, bp2, out, n);
}

// Round 2
// 251.745 us; speedup vs baseline: 1.2505x; 1.2505x over previous
//
#include <hip/hip_runtime.h>

#define FH 240
#define FW 240
#define FC 64
constexpr float IMG = 960.0f;

// ---------------- ws layout (floats) ----------------
static constexpr int WS_FMT = 0;          // fmT [240][240][64]
static constexpr int WS_G   = 3686400;    // g   [64]
static constexpr int WS_HG  = 3686464;    // hg  [64]
static constexpr int WS_POOL= 3686528;    // pooled [N][192]

// ---------- Kernel 1: transpose fm [C,H,W] -> fmT [H,W,C] ----------
__global__ __launch_bounds__(256) void k_transpose(const float* __restrict__ fm,
                                                   float* __restrict__ fmT) {
    __shared__ float tile[64][65];
    int y  = blockIdx.y;
    int x0 = blockIdx.x * 64;
    int tid = threadIdx.x;
    int lane = tid & 63;
    int wv   = tid >> 6;
    int x = x0 + lane;
    bool xin = (x < FW);
    #pragma unroll
    for (int k = 0; k < 16; ++k) {
        int c = wv + k * 4;
        tile[c][lane] = xin ? fm[c * (FH * FW) + y * FW + x] : 0.0f;
    }
    __syncthreads();
    #pragma unroll
    for (int k = 0; k < 16; ++k) {
        int idx = tid + k * 256;      // 0..4095
        int xl = idx >> 6;
        int c  = idx & 63;
        int xx = x0 + xl;
        if (xx < FW) fmT[(y * FW + xx) * 64 + c] = tile[c][xl];
    }
}

// ---------- Kernel 2: per-channel global mean ----------
__global__ __launch_bounds__(256) void k_gmean(const float* __restrict__ fm,
                                               float* __restrict__ g) {
    int c = blockIdx.x;
    const float* p = fm + c * (FH * FW);
    float s = 0.0f;
    for (int i = threadIdx.x; i < FH * FW; i += 256) s += p[i];
    __shared__ float red[256];
    red[threadIdx.x] = s;
    __syncthreads();
    for (int st = 128; st > 0; st >>= 1) {
        if (threadIdx.x < st) red[threadIdx.x] += red[threadIdx.x + st];
        __syncthreads();
    }
    if (threadIdx.x == 0) g[c] = red[0] / (float)(FH * FW);
}

// ---------- Kernel 3: hg = head(g) (single tiny block) ----------
__global__ __launch_bounds__(128) void k_headg(const float* __restrict__ g,
                                               const float* __restrict__ W1, const float* __restrict__ b1,
                                               const float* __restrict__ W2, const float* __restrict__ b2,
                                               float* __restrict__ hg) {
    __shared__ float gs[64];
    __shared__ float h1[128];
    int t = threadIdx.x;
    if (t < 64) gs[t] = g[t];
    __syncthreads();
    float acc = b1[t];
    for (int c = 0; c < 64; ++c) acc += gs[c] * W1[c * 128 + t];
    h1[t] = fmaxf(acc, 0.0f);
    __syncthreads();
    if (t < 64) {
        float a2 = b2[t];
        for (int j = 0; j < 128; ++j) a2 += h1[j] * W2[j * 64 + t];
        hg[t] = fmaxf(a2, 0.0f);
    }
}

// ---------- Kernel 4: ROI bilinear pooling (two-phase) ----------
// Phase 1: one thread per sample computes offsets/weights once -> LDS.
// Phase 2: 16 sample-slots x 16 lanes; each lane owns 4 contiguous channels
//          (float4 gathers). LDS partial reduce -> pooled[box][192].
#define NSAMP 179   // 9 + 49 + 121

__global__ __launch_bounds__(256) void k_pool(const float* __restrict__ fmT,
                                              const float* __restrict__ boxes,
                                              float* __restrict__ pooled) {
    __shared__ int   smp[NSAMP * 8];       // per sample: 4 int offsets + 4 float weights
    __shared__ float part[3 * 16 * 64];    // [scale][slot][channel]

    int box = blockIdx.x;
    int tid = threadIdx.x;

    // --- Phase 1 ---
    if (tid < NSAMP) {
        float bx1 = boxes[box * 4 + 0], by1 = boxes[box * 4 + 1];
        float bx2 = boxes[box * 4 + 2], by2 = boxes[box * 4 + 3];
        float x1n = (bx1 / IMG) * 2.0f - 1.0f;
        float y1n = (by1 / IMG) * 2.0f - 1.0f;
        float x2n = (bx2 / IMG) * 2.0f - 1.0f;
        float y2n = (by2 / IMG) * 2.0f - 1.0f;
        float cx = (x1n + x2n) * 0.5f, cy = (y1n + y2n) * 0.5f;
        float w2 = fmaxf(x2n - x1n, 1e-6f) * 0.5f;
        float h2 = fmaxf(y2n - y1n, 1e-6f) * 0.5f;

        int S, s;
        if (tid < 9)       { S = 3;  s = tid; }
        else if (tid < 58) { S = 7;  s = tid - 9; }
        else               { S = 11; s = tid - 58; }
        int i = s / S;
        int j = s - i * S;
        float Sf = (float)S;
        float bj = (2.0f * (float)j + 1.0f) / Sf - 1.0f;
        float bi = (2.0f * (float)i + 1.0f) / Sf - 1.0f;
        float gx = w2 * bj + cx;
        float gy = h2 * bi + cy;
        float ix = ((gx + 1.0f) * 240.0f - 1.0f) * 0.5f;
        float iy = ((gy + 1.0f) * 240.0f - 1.0f) * 0.5f;
        float x0f = floorf(ix), y0f = floorf(iy);
        float dx = ix - x0f,    dy = iy - y0f;
        int x0 = (int)x0f, y0 = (int)y0f;
        int x1 = x0 + 1,   y1 = y0 + 1;
        float inv = 1.0f / (Sf * Sf);
        float wx0 = (x0 >= 0 && x0 < FW) ? (1.0f - dx) : 0.0f;
        float wx1 = (x1 >= 0 && x1 < FW) ? dx          : 0.0f;
        float wy0 = (y0 >= 0 && y0 < FH) ? (1.0f - dy) : 0.0f;
        float wy1 = (y1 >= 0 && y1 < FH) ? dy          : 0.0f;
        int x0c = min(max(x0, 0), FW - 1), x1c = min(max(x1, 0), FW - 1);
        int y0c = min(max(y0, 0), FH - 1), y1c = min(max(y1, 0), FH - 1);
        int r0 = y0c * FW, r1 = y1c * FW;
        smp[tid * 8 + 0] = (r0 + x0c) * 64;
        smp[tid * 8 + 1] = (r0 + x1c) * 64;
        smp[tid * 8 + 2] = (r1 + x0c) * 64;
        smp[tid * 8 + 3] = (r1 + x1c) * 64;
        float* wp = (float*)&smp[tid * 8 + 4];
        wp[0] = wx0 * wy0 * inv;
        wp[1] = wx1 * wy0 * inv;
        wp[2] = wx0 * wy1 * inv;
        wp[3] = wx1 * wy1 * inv;
    }
    __syncthreads();

    // --- Phase 2 ---
    int slot = tid >> 4;        // 0..15
    int l    = tid & 15;
    int c4   = l << 2;          // channel base (0,4,...,60)

    float a[3][4];
    #pragma unroll
    for (int sc = 0; sc < 3; ++sc)
        #pragma unroll
        for (int k = 0; k < 4; ++k) a[sc][k] = 0.0f;

    const int start[3] = {0, 9, 58};
    const int end_[3]  = {9, 58, NSAMP};
    #pragma unroll
    for (int sc = 0; sc < 3; ++sc) {
        for (int s = start[sc] + slot; s < end_[sc]; s += 16) {
            int4   bo = *(const int4*)  &smp[s * 8];
            float4 wv = *(const float4*)&smp[s * 8 + 4];
            float4 v00 = *(const float4*)(fmT + bo.x + c4);
            float4 v01 = *(const float4*)(fmT + bo.y + c4);
            float4 v10 = *(const float4*)(fmT + bo.z + c4);
            float4 v11 = *(const float4*)(fmT + bo.w + c4);
            a[sc][0] += wv.x * v00.x + wv.y * v01.x + wv.z * v10.x + wv.w * v11.x;
            a[sc][1] += wv.x * v00.y + wv.y * v01.y + wv.z * v10.y + wv.w * v11.y;
            a[sc][2] += wv.x * v00.z + wv.y * v01.z + wv.z * v10.z + wv.w * v11.z;
            a[sc][3] += wv.x * v00.w + wv.y * v01.w + wv.z * v10.w + wv.w * v11.w;
        }
    }
    #pragma unroll
    for (int sc = 0; sc < 3; ++sc) {
        float* pp = &part[(sc * 16 + slot) * 64 + c4];
        pp[0] = a[sc][0]; pp[1] = a[sc][1]; pp[2] = a[sc][2]; pp[3] = a[sc][3];
    }
    __syncthreads();

    // --- Reduce 16 slots -> pooled ---
    if (tid < 192) {
        int sc = tid >> 6, c = tid & 63;
        float sum = 0.0f;
        #pragma unroll
        for (int q = 0; q < 16; ++q) sum += part[(sc * 16 + q) * 64 + c];
        pooled[(size_t)box * 192 + tid] = sum;
    }
}

// ---------- Kernel 5: heads (3 scales) + final MLP, 8 rows per block ----------
__global__ __launch_bounds__(256) void k_mlp(const float* __restrict__ pooled,
                                             const float* __restrict__ hg,
                                             const float* __restrict__ W1, const float* __restrict__ b1,
                                             const float* __restrict__ W2, const float* __restrict__ b2,
                                             const float* __restrict__ P1, const float* __restrict__ bp1,
                                             const float* __restrict__ P2, const float* __restrict__ bp2,
                                             float* __restrict__ out, int n) {
    constexpr int NB = 8;
    __shared__ float pool_l[NB][192];
    __shared__ float catf[NB][256];
    __shared__ float h1_l[NB][128];
    __shared__ float scratch[4 * NB * 128];
    int tid = threadIdx.x;
    int box0 = blockIdx.x * NB;

    for (int idx = tid; idx < NB * 192; idx += 256) {
        int r = idx / 192, cc = idx - r * 192;
        pool_l[r][cc] = (box0 + r < n) ? pooled[(size_t)(box0 + r) * 192 + cc] : 0.0f;
    }
    for (int idx = tid; idx < NB * 64; idx += 256) {
        int r = idx >> 6, k = idx & 63;
        catf[r][192 + k] = hg[k];
    }
    __syncthreads();

    int j = tid & 127, half = tid >> 7;   // stage-1 mapping
    int k = tid & 63,  q    = tid >> 6;   // stage-2 mapping

    for (int sc = 0; sc < 3; ++sc) {
        float acc[NB];
        #pragma unroll
        for (int r = 0; r < NB; ++r) acc[r] = 0.0f;
        for (int c = half * 32; c < half * 32 + 32; ++c) {
            float wv = W1[c * 128 + j];
            #pragma unroll
            for (int r = 0; r < NB; ++r) acc[r] += pool_l[r][sc * 64 + c] * wv;
        }
        #pragma unroll
        for (int r = 0; r < NB; ++r) scratch[(half * NB + r) * 128 + j] = acc[r];
        __syncthreads();
        if (half == 0) {
            float bb = b1[j];
            #pragma unroll
            for (int r = 0; r < NB; ++r)
                h1_l[r][j] = fmaxf(scratch[r * 128 + j] + scratch[(NB + r) * 128 + j] + bb, 0.0f);
        }
        __syncthreads();
        float a2[NB];
        #pragma unroll
        for (int r = 0; r < NB; ++r) a2[r] = 0.0f;
        for (int jj = q * 32; jj < q * 32 + 32; ++jj) {
            float wv = W2[jj * 64 + k];
            #pragma unroll
            for (int r = 0; r < NB; ++r) a2[r] += h1_l[r][jj] * wv;
        }
        #pragma unroll
        for (int r = 0; r < NB; ++r) scratch[(q * NB + r) * 64 + k] = a2[r];
        __syncthreads();
        if (q == 0) {
            float bb = b2[k];
            #pragma unroll
            for (int r = 0; r < NB; ++r) {
                float v = scratch[r * 64 + k] + scratch[(NB + r) * 64 + k] +
                          scratch[(2 * NB + r) * 64 + k] + scratch[(3 * NB + r) * 64 + k] + bb;
                catf[r][sc * 64 + k] = fmaxf(v, 0.0f);
            }
        }
        __syncthreads();
    }

    float acc[NB];
    #pragma unroll
    for (int r = 0; r < NB; ++r) acc[r] = 0.0f;
    for (int c = half * 128; c < half * 128 + 128; ++c) {
        float wv = P1[c * 128 + j];
        #pragma unroll
        for (int r = 0; r < NB; ++r) acc[r] += catf[r][c] * wv;
    }
    #pragma unroll
    for (int r = 0; r < NB; ++r) scratch[(half * NB + r) * 128 + j] = acc[r];
    __syncthreads();
    if (half == 0) {
        float bb = bp1[j];
        #pragma unroll
        for (int r = 0; r < NB; ++r)
            h1_l[r][j] = fmaxf(scratch[r * 128 + j] + scratch[(NB + r) * 128 + j] + bb, 0.0f);
    }
    __syncthreads();
    float a2[NB];
    #pragma unroll
    for (int r = 0; r < NB; ++r) a2[r] = 0.0f;
    for (int jj = q * 32; jj < q * 32 + 32; ++jj) {
        float wv = P2[jj * 64 + k];
        #pragma unroll
        for (int r = 0; r < NB; ++r) a2[r] += h1_l[r][jj] * wv;
    }
    #pragma unroll
    for (int r = 0; r < NB; ++r) scratch[(q * NB + r) * 64 + k] = a2[r];
    __syncthreads();
    if (q == 0) {
        float bb = bp2[k];
        #pragma unroll
        for (int r = 0; r < NB; ++r) {
            if (box0 + r < n) {
                float v = scratch[r * 64 + k] + scratch[(NB + r) * 64 + k] +
                          scratch[(2 * NB + r) * 64 + k] + scratch[(3 * NB + r) * 64 + k] + bb;
                out[(size_t)(box0 + r) * 64 + k] = fmaxf(v, 0.0f);
            }
        }
    }
}

extern "C" void kernel_launch(void* const* d_in, const int* in_sizes, int n_in,
                              void* d_out, int out_size, void* d_ws, size_t ws_size,
                              hipStream_t stream) {
    const float* fm    = (const float*)d_in[0];
    const float* boxes = (const float*)d_in[1];
    const float* W1    = (const float*)d_in[2];
    const float* b1    = (const float*)d_in[3];
    const float* W2    = (const float*)d_in[4];
    const float* b2    = (const float*)d_in[5];
    const float* P1    = (const float*)d_in[6];
    const float* bp1   = (const float*)d_in[7];
    const float* P2    = (const float*)d_in[8];
    const float* bp2   = (const float*)d_in[9];
    float* ws = (float*)d_ws;
    float* fmT    = ws + WS_FMT;
    float* g      = ws + WS_G;
    float* hg     = ws + WS_HG;
    float* pooled = ws + WS_POOL;
    float* out = (float*)d_out;
    int n = in_sizes[1] / 4;   // 4000 boxes

    k_transpose<<<dim3(4, 240), 256, 0, stream>>>(fm, fmT);
    k_gmean<<<64, 256, 0, stream>>>(fm, g);
    k_headg<<<1, 128, 0, stream>>>(g, W1, b1, W2, b2, hg);
    k_pool<<<n, 256, 0, stream>>>(fmT, boxes, pooled);
    k_mlp<<<(n + 7) / 8, 256, 0, stream>>>(pooled, hg, W1, b1, W2, b2,
                                           P1, bp1, P2, bp2, out, n);
}

// Round 3
// 199.355 us; speedup vs baseline: 1.5792x; 1.2628x over previous
//
#include <hip/hip_runtime.h>

#define FH 240
#define FW 240
constexpr float IMG = 960.0f;

// ---------------- ws layout (floats) ----------------
static constexpr int WS_FMT  = 0;          // fmT [240][240][64]
static constexpr int WS_GP   = 3686400;    // gpart [4][64]
static constexpr int WS_POOL = 3686656;    // pooled [N][192]

// ---------- Kernel 1: transpose fm [C,H,W] -> fmT [H,W,C] ----------
__global__ __launch_bounds__(256) void k_transpose(const float* __restrict__ fm,
                                                   float* __restrict__ fmT) {
    __shared__ float tile[64][65];
    int y  = blockIdx.y;
    int x0 = blockIdx.x * 64;
    int tid = threadIdx.x;
    int lane = tid & 63;
    int wv   = tid >> 6;
    int x = x0 + lane;
    bool xin = (x < FW);
    #pragma unroll
    for (int k = 0; k < 16; ++k) {
        int c = wv + k * 4;
        tile[c][lane] = xin ? fm[c * (FH * FW) + y * FW + x] : 0.0f;
    }
    __syncthreads();
    #pragma unroll
    for (int k = 0; k < 16; ++k) {
        int idx = tid + k * 256;      // 0..4095
        int xl = idx >> 6;
        int c  = idx & 63;
        int xx = x0 + xl;
        if (xx < FW) fmT[(y * FW + xx) * 64 + c] = tile[c][xl];
    }
}

// ---------- Kernel 2: per-channel partial sums (256 blocks) ----------
__global__ __launch_bounds__(256) void k_gpart(const float* __restrict__ fm,
                                               float* __restrict__ gpart) {
    int b = blockIdx.x;           // 0..255
    int c = b >> 2, q = b & 3;    // channel, quarter
    const float* p = fm + c * (FH * FW) + q * 14400;
    float s = 0.0f;
    for (int i = threadIdx.x; i < 14400; i += 256) s += p[i];
    __shared__ float red[256];
    red[threadIdx.x] = s;
    __syncthreads();
    for (int st = 128; st > 0; st >>= 1) {
        if (threadIdx.x < st) red[threadIdx.x] += red[threadIdx.x + st];
        __syncthreads();
    }
    if (threadIdx.x == 0) gpart[q * 64 + c] = red[0];
}

// ---------- Kernel 3: ROI bilinear pooling (two-phase) ----------
#define NSAMP 179   // 9 + 49 + 121

__global__ __launch_bounds__(256) void k_pool(const float* __restrict__ fmT,
                                              const float* __restrict__ boxes,
                                              float* __restrict__ pooled) {
    __shared__ int   smp[NSAMP * 8];       // per sample: 4 int offsets + 4 float weights
    __shared__ float part[3 * 16 * 64];    // [scale][slot][channel]

    int box = blockIdx.x;
    int tid = threadIdx.x;

    // --- Phase 1: one thread per sample ---
    if (tid < NSAMP) {
        float bx1 = boxes[box * 4 + 0], by1 = boxes[box * 4 + 1];
        float bx2 = boxes[box * 4 + 2], by2 = boxes[box * 4 + 3];
        float x1n = (bx1 / IMG) * 2.0f - 1.0f;
        float y1n = (by1 / IMG) * 2.0f - 1.0f;
        float x2n = (bx2 / IMG) * 2.0f - 1.0f;
        float y2n = (by2 / IMG) * 2.0f - 1.0f;
        float cx = (x1n + x2n) * 0.5f, cy = (y1n + y2n) * 0.5f;
        float w2 = fmaxf(x2n - x1n, 1e-6f) * 0.5f;
        float h2 = fmaxf(y2n - y1n, 1e-6f) * 0.5f;

        int S, s;
        if (tid < 9)       { S = 3;  s = tid; }
        else if (tid < 58) { S = 7;  s = tid - 9; }
        else               { S = 11; s = tid - 58; }
        int i = s / S;
        int j = s - i * S;
        float Sf = (float)S;
        float bj = (2.0f * (float)j + 1.0f) / Sf - 1.0f;
        float bi = (2.0f * (float)i + 1.0f) / Sf - 1.0f;
        float gx = w2 * bj + cx;
        float gy = h2 * bi + cy;
        float ix = ((gx + 1.0f) * 240.0f - 1.0f) * 0.5f;
        float iy = ((gy + 1.0f) * 240.0f - 1.0f) * 0.5f;
        float x0f = floorf(ix), y0f = floorf(iy);
        float dx = ix - x0f,    dy = iy - y0f;
        int x0 = (int)x0f, y0 = (int)y0f;
        int x1 = x0 + 1,   y1 = y0 + 1;
        float inv = 1.0f / (Sf * Sf);
        float wx0 = (x0 >= 0 && x0 < FW) ? (1.0f - dx) : 0.0f;
        float wx1 = (x1 >= 0 && x1 < FW) ? dx          : 0.0f;
        float wy0 = (y0 >= 0 && y0 < FH) ? (1.0f - dy) : 0.0f;
        float wy1 = (y1 >= 0 && y1 < FH) ? dy          : 0.0f;
        int x0c = min(max(x0, 0), FW - 1), x1c = min(max(x1, 0), FW - 1);
        int y0c = min(max(y0, 0), FH - 1), y1c = min(max(y1, 0), FH - 1);
        int r0 = y0c * FW, r1 = y1c * FW;
        smp[tid * 8 + 0] = (r0 + x0c) * 64;
        smp[tid * 8 + 1] = (r0 + x1c) * 64;
        smp[tid * 8 + 2] = (r1 + x0c) * 64;
        smp[tid * 8 + 3] = (r1 + x1c) * 64;
        float* wp = (float*)&smp[tid * 8 + 4];
        wp[0] = wx0 * wy0 * inv;
        wp[1] = wx1 * wy0 * inv;
        wp[2] = wx0 * wy1 * inv;
        wp[3] = wx1 * wy1 * inv;
    }
    __syncthreads();

    // --- Phase 2: 16 slots x 16 lanes, float4 gathers ---
    int slot = tid >> 4;
    int l    = tid & 15;
    int c4   = l << 2;

    float a[3][4];
    #pragma unroll
    for (int sc = 0; sc < 3; ++sc)
        #pragma unroll
        for (int k = 0; k < 4; ++k) a[sc][k] = 0.0f;

    const int start[3] = {0, 9, 58};
    const int end_[3]  = {9, 58, NSAMP};
    #pragma unroll
    for (int sc = 0; sc < 3; ++sc) {
        for (int s = start[sc] + slot; s < end_[sc]; s += 16) {
            int4   bo = *(const int4*)  &smp[s * 8];
            float4 wv = *(const float4*)&smp[s * 8 + 4];
            float4 v00 = *(const float4*)(fmT + bo.x + c4);
            float4 v01 = *(const float4*)(fmT + bo.y + c4);
            float4 v10 = *(const float4*)(fmT + bo.z + c4);
            float4 v11 = *(const float4*)(fmT + bo.w + c4);
            a[sc][0] += wv.x * v00.x + wv.y * v01.x + wv.z * v10.x + wv.w * v11.x;
            a[sc][1] += wv.x * v00.y + wv.y * v01.y + wv.z * v10.y + wv.w * v11.y;
            a[sc][2] += wv.x * v00.z + wv.y * v01.z + wv.z * v10.z + wv.w * v11.z;
            a[sc][3] += wv.x * v00.w + wv.y * v01.w + wv.z * v10.w + wv.w * v11.w;
        }
    }
    #pragma unroll
    for (int sc = 0; sc < 3; ++sc) {
        float* pp = &part[(sc * 16 + slot) * 64 + c4];
        pp[0] = a[sc][0]; pp[1] = a[sc][1]; pp[2] = a[sc][2]; pp[3] = a[sc][3];
    }
    __syncthreads();

    if (tid < 192) {
        int sc = tid >> 6, c = tid & 63;
        float sum = 0.0f;
        #pragma unroll
        for (int q = 0; q < 16; ++q) sum += part[(sc * 16 + q) * 64 + c];
        pooled[(size_t)box * 192 + tid] = sum;
    }
}

// ---------- Kernel 4: heads (3 scales + g-row) + final MLP ----------
// 8 boxes per block. Row batch m=0..24: m<24 -> (scale=m>>3, box=m&7), m=24 -> g.
// Rows 25..27 are zero/garbage padding (outputs discarded).
__global__ __launch_bounds__(256) void k_mlp(const float* __restrict__ pooled,
                                             const float* __restrict__ gpart,
                                             const float* __restrict__ W1, const float* __restrict__ b1,
                                             const float* __restrict__ W2, const float* __restrict__ b2,
                                             const float* __restrict__ P1, const float* __restrict__ bp1,
                                             const float* __restrict__ P2, const float* __restrict__ bp2,
                                             float* __restrict__ out, int n) {
    __shared__ float inp[26][64];     // 25 input rows + zero row
    __shared__ float h1[28][128];     // stage1 out; rows 0..7 reused as stage3 out
    __shared__ float catf[8][256];
    int tid = threadIdx.x;
    int box0 = blockIdx.x * 8;

    // ---- load inputs ----
    #pragma unroll
    for (int it = 0; it < 6; ++it) {
        int idx = tid + it * 256;          // < 1536 = 24*64
        int m = idx >> 6, c = idx & 63;
        int rb = m & 7, sc = m >> 3;
        inp[m][c] = (box0 + rb < n) ? pooled[(size_t)(box0 + rb) * 192 + sc * 64 + c] : 0.0f;
    }
    if (tid < 64) {
        float s = gpart[tid] + gpart[64 + tid] + gpart[128 + tid] + gpart[192 + tid];
        inp[24][tid] = s * (1.0f / (float)(FH * FW));
        inp[25][tid] = 0.0f;
    }
    ((float*)h1)[26 * 128 + tid] = 0.0f;   // zero pad rows 26,27
    __syncthreads();

    // ---- Stage 1: h1[m][j] = relu(inp[m] @ W1 + b1), m in 0..25 ----
    {
        int j = tid & 127, grp = tid >> 7;
        int m0 = grp * 13;
        float acc[13];
        #pragma unroll
        for (int r = 0; r < 13; ++r) acc[r] = 0.0f;
        for (int c = 0; c < 64; c += 4) {
            float w0 = W1[(c    ) * 128 + j];
            float w1 = W1[(c + 1) * 128 + j];
            float w2 = W1[(c + 2) * 128 + j];
            float w3 = W1[(c + 3) * 128 + j];
            #pragma unroll
            for (int r = 0; r < 13; ++r) {
                float4 x = *(const float4*)&inp[m0 + r][c];
                acc[r] = fmaf(x.x, w0, fmaf(x.y, w1, fmaf(x.z, w2, fmaf(x.w, w3, acc[r]))));
            }
        }
        float bb = b1[j];
        #pragma unroll
        for (int r = 0; r < 13; ++r) h1[m0 + r][j] = fmaxf(acc[r] + bb, 0.0f);
    }
    __syncthreads();

    // ---- Stage 2: h2[m][k] = relu(h1[m] @ W2 + b2) -> catf / hg ----
    {
        int k = tid & 63, q = tid >> 6;
        int m0 = q * 7;
        float acc[7];
        #pragma unroll
        for (int r = 0; r < 7; ++r) acc[r] = 0.0f;
        for (int jj = 0; jj < 128; jj += 4) {
            float w0 = W2[(jj    ) * 64 + k];
            float w1 = W2[(jj + 1) * 64 + k];
            float w2 = W2[(jj + 2) * 64 + k];
            float w3 = W2[(jj + 3) * 64 + k];
            #pragma unroll
            for (int r = 0; r < 7; ++r) {
                float4 x = *(const float4*)&h1[m0 + r][jj];
                acc[r] = fmaf(x.x, w0, fmaf(x.y, w1, fmaf(x.z, w2, fmaf(x.w, w3, acc[r]))));
            }
        }
        float bb = b2[k];
        #pragma unroll
        for (int r = 0; r < 7; ++r) {
            int m = m0 + r;
            float v = fmaxf(acc[r] + bb, 0.0f);
            if (m < 24) {
                catf[m & 7][(m >> 3) * 64 + k] = v;
            } else if (m == 24) {
                #pragma unroll
                for (int rr = 0; rr < 8; ++rr) catf[rr][192 + k] = v;
            }
        }
    }
    __syncthreads();

    // ---- Stage 3: hid[r][j] = relu(catf[r] @ P1 + bp1) -> h1 rows 0..7 ----
    {
        int j = tid & 127, grp = tid >> 7;
        int r0 = grp * 4;
        float acc[4] = {0.0f, 0.0f, 0.0f, 0.0f};
        for (int c = 0; c < 256; c += 4) {
            float w0 = P1[(c    ) * 128 + j];
            float w1 = P1[(c + 1) * 128 + j];
            float w2 = P1[(c + 2) * 128 + j];
            float w3 = P1[(c + 3) * 128 + j];
            #pragma unroll
            for (int r = 0; r < 4; ++r) {
                float4 x = *(const float4*)&catf[r0 + r][c];
                acc[r] = fmaf(x.x, w0, fmaf(x.y, w1, fmaf(x.z, w2, fmaf(x.w, w3, acc[r]))));
            }
        }
        float bb = bp1[j];
        #pragma unroll
        for (int r = 0; r < 4; ++r) h1[r0 + r][j] = fmaxf(acc[r] + bb, 0.0f);
    }
    __syncthreads();

    // ---- Stage 4: out[r][k] = relu(hid[r] @ P2 + bp2) ----
    {
        int k = tid & 63, q = tid >> 6;
        int r0 = q * 2;
        float acc[2] = {0.0f, 0.0f};
        for (int jj = 0; jj < 128; jj += 4) {
            float w0 = P2[(jj    ) * 64 + k];
            float w1 = P2[(jj + 1) * 64 + k];
            float w2 = P2[(jj + 2) * 64 + k];
            float w3 = P2[(jj + 3) * 64 + k];
            #pragma unroll
            for (int r = 0; r < 2; ++r) {
                float4 x = *(const float4*)&h1[r0 + r][jj];
                acc[r] = fmaf(x.x, w0, fmaf(x.y, w1, fmaf(x.z, w2, fmaf(x.w, w3, acc[r]))));
            }
        }
        float bb = bp2[k];
        #pragma unroll
        for (int r = 0; r < 2; ++r) {
            int row = box0 + r0 + r;
            if (row < n) out[(size_t)row * 64 + k] = fmaxf(acc[r] + bb, 0.0f);
        }
    }
}

extern "C" void kernel_launch(void* const* d_in, const int* in_sizes, int n_in,
                              void* d_out, int out_size, void* d_ws, size_t ws_size,
                              hipStream_t stream) {
    const float* fm    = (const float*)d_in[0];
    const float* boxes = (const float*)d_in[1];
    const float* W1    = (const float*)d_in[2];
    const float* b1    = (const float*)d_in[3];
    const float* W2    = (const float*)d_in[4];
    const float* b2    = (const float*)d_in[5];
    const float* P1    = (const float*)d_in[6];
    const float* bp1   = (const float*)d_in[7];
    const float* P2    = (const float*)d_in[8];
    const float* bp2   = (const float*)d_in[9];
    float* ws = (float*)d_ws;
    float* fmT    = ws + WS_FMT;
    float* gpart  = ws + WS_GP;
    float* pooled = ws + WS_POOL;
    float* out = (float*)d_out;
    int n = in_sizes[1] / 4;   // 4000 boxes

    k_transpose<<<dim3(4, 240), 256, 0, stream>>>(fm, fmT);
    k_gpart<<<256, 256, 0, stream>>>(fm, gpart);
    k_pool<<<n, 256, 0, stream>>>(fmT, boxes, pooled);
    k_mlp<<<(n + 7) / 8, 256, 0, stream>>>(pooled, gpart, W1, b1, W2, b2,
                                           P1, bp1, P2, bp2, out, n);
}

// Round 4
// 169.492 us; speedup vs baseline: 1.8574x; 1.1762x over previous
//
#include <hip/hip_runtime.h>
#include <hip/hip_fp16.h>

#define FH 240
#define FW 240
constexpr float IMG = 960.0f;

// ---------------- ws layout (floats) ----------------
static constexpr int WS_FMT  = 0;          // fmT fp16 [240][240][64] = 1,843,200 floats
static constexpr int WS_GP   = 3686400;    // gpart [64] (atomic-accumulated)
static constexpr int WS_POOL = 3686656;    // pooled [N][192]

// ---------- Kernel 1: transpose fm [C,H,W] -> fp16 fmT [H,W,C], + channel sums ----------
__global__ __launch_bounds__(256) void k_transpose(const float* __restrict__ fm,
                                                   __half* __restrict__ fmT,
                                                   float* __restrict__ gpart) {
    __shared__ float tile[64][65];
    int y  = blockIdx.y;
    int x0 = blockIdx.x * 64;
    int tid = threadIdx.x;
    int lane = tid & 63;
    int wv   = tid >> 6;
    int x = x0 + lane;
    bool xin = (x < FW);
    #pragma unroll
    for (int k = 0; k < 16; ++k) {
        int c = wv + k * 4;
        tile[c][lane] = xin ? fm[c * (FH * FW) + y * FW + x] : 0.0f;
    }
    __syncthreads();

    // fused per-channel partial sum (zeros in pad lanes contribute nothing)
    if (tid < 64) {
        float s = 0.0f;
        #pragma unroll
        for (int i = 0; i < 64; ++i) s += tile[tid][i];
        atomicAdd(gpart + tid, s);
    }

    // write fp16, 8 channels per thread (16 B stores), 2 iterations
    #pragma unroll
    for (int it = 0; it < 2; ++it) {
        int idx = tid + it * 256;       // 0..511
        int xl  = idx >> 3;             // 0..63
        int co  = (idx & 7) * 8;        // 0,8,...,56
        int xx  = x0 + xl;
        if (xx < FW) {
            union { float4 f4; __half2 h2[4]; } u;
            #pragma unroll
            for (int i = 0; i < 4; ++i)
                u.h2[i] = __floats2half2_rn(tile[co + 2*i][xl], tile[co + 2*i + 1][xl]);
            *(float4*)&fmT[((size_t)(y * FW + xx)) * 64 + co] = u.f4;
        }
    }
}

// ---------- Kernel 2: ROI bilinear pooling (two-phase, fp16 gathers) ----------
#define NSAMP 179   // 9 + 49 + 121

__device__ __forceinline__ void acc8(float* a, const __half* __restrict__ base,
                                     int off, int c8, float w) {
    float4 raw = *(const float4*)(base + off + c8);   // 8 fp16
    const __half2* h = (const __half2*)&raw;
    #pragma unroll
    for (int i = 0; i < 4; ++i) {
        float2 f = __half22float2(h[i]);
        a[2*i]     = fmaf(w, f.x, a[2*i]);
        a[2*i + 1] = fmaf(w, f.y, a[2*i + 1]);
    }
}

__global__ __launch_bounds__(256) void k_pool(const __half* __restrict__ fmT,
                                              const float* __restrict__ boxes,
                                              float* __restrict__ pooled) {
    __shared__ int   smp[NSAMP * 8];        // per sample: 4 int offsets + 4 float weights
    __shared__ float part[3][64 * 33];      // [scale][c*33 + slot], stride 33 kills conflicts

    int box = blockIdx.x;
    int tid = threadIdx.x;

    // --- Phase 1: one thread per sample ---
    if (tid < NSAMP) {
        float bx1 = boxes[box * 4 + 0], by1 = boxes[box * 4 + 1];
        float bx2 = boxes[box * 4 + 2], by2 = boxes[box * 4 + 3];
        float x1n = (bx1 / IMG) * 2.0f - 1.0f;
        float y1n = (by1 / IMG) * 2.0f - 1.0f;
        float x2n = (bx2 / IMG) * 2.0f - 1.0f;
        float y2n = (by2 / IMG) * 2.0f - 1.0f;
        float cx = (x1n + x2n) * 0.5f, cy = (y1n + y2n) * 0.5f;
        float w2 = fmaxf(x2n - x1n, 1e-6f) * 0.5f;
        float h2 = fmaxf(y2n - y1n, 1e-6f) * 0.5f;

        int S, s;
        if (tid < 9)       { S = 3;  s = tid; }
        else if (tid < 58) { S = 7;  s = tid - 9; }
        else               { S = 11; s = tid - 58; }
        int i = s / S;
        int j = s - i * S;
        float Sf = (float)S;
        float bj = (2.0f * (float)j + 1.0f) / Sf - 1.0f;
        float bi = (2.0f * (float)i + 1.0f) / Sf - 1.0f;
        float gx = w2 * bj + cx;
        float gy = h2 * bi + cy;
        float ix = ((gx + 1.0f) * 240.0f - 1.0f) * 0.5f;
        float iy = ((gy + 1.0f) * 240.0f - 1.0f) * 0.5f;
        float x0f = floorf(ix), y0f = floorf(iy);
        float dx = ix - x0f,    dy = iy - y0f;
        int x0 = (int)x0f, y0 = (int)y0f;
        int x1 = x0 + 1,   y1 = y0 + 1;
        float inv = 1.0f / (Sf * Sf);
        float wx0 = (x0 >= 0 && x0 < FW) ? (1.0f - dx) : 0.0f;
        float wx1 = (x1 >= 0 && x1 < FW) ? dx          : 0.0f;
        float wy0 = (y0 >= 0 && y0 < FH) ? (1.0f - dy) : 0.0f;
        float wy1 = (y1 >= 0 && y1 < FH) ? dy          : 0.0f;
        int x0c = min(max(x0, 0), FW - 1), x1c = min(max(x1, 0), FW - 1);
        int y0c = min(max(y0, 0), FH - 1), y1c = min(max(y1, 0), FH - 1);
        int r0 = y0c * FW, r1 = y1c * FW;
        smp[tid * 8 + 0] = (r0 + x0c) * 64;
        smp[tid * 8 + 1] = (r0 + x1c) * 64;
        smp[tid * 8 + 2] = (r1 + x0c) * 64;
        smp[tid * 8 + 3] = (r1 + x1c) * 64;
        float* wp = (float*)&smp[tid * 8 + 4];
        wp[0] = wx0 * wy0 * inv;
        wp[1] = wx1 * wy0 * inv;
        wp[2] = wx0 * wy1 * inv;
        wp[3] = wx1 * wy1 * inv;
    }
    __syncthreads();

    // --- Phase 2: 32 slots x 8 lanes, 8 channels/lane, fp16 16-B gathers ---
    int slot = tid >> 3;        // 0..31
    int l    = tid & 7;
    int c8   = l << 3;          // 0,8,...,56

    float a[3][8];
    #pragma unroll
    for (int sc = 0; sc < 3; ++sc)
        #pragma unroll
        for (int k = 0; k < 8; ++k) a[sc][k] = 0.0f;

    const int start[3] = {0, 9, 58};
    const int end_[3]  = {9, 58, NSAMP};
    #pragma unroll
    for (int sc = 0; sc < 3; ++sc) {
        for (int s = start[sc] + slot; s < end_[sc]; s += 32) {
            int4   bo = *(const int4*)  &smp[s * 8];
            float4 wv = *(const float4*)&smp[s * 8 + 4];
            acc8(a[sc], fmT, bo.x, c8, wv.x);
            acc8(a[sc], fmT, bo.y, c8, wv.y);
            acc8(a[sc], fmT, bo.z, c8, wv.z);
            acc8(a[sc], fmT, bo.w, c8, wv.w);
        }
    }
    #pragma unroll
    for (int sc = 0; sc < 3; ++sc)
        #pragma unroll
        for (int i = 0; i < 8; ++i)
            part[sc][(c8 + i) * 33 + slot] = a[sc][i];
    __syncthreads();

    // --- Reduce 32 slots -> pooled[box][192] ---
    if (tid < 192) {
        int sc = tid >> 6, c = tid & 63;
        float sum = 0.0f;
        #pragma unroll
        for (int q = 0; q < 32; ++q) sum += part[sc][c * 33 + q];
        pooled[(size_t)box * 192 + tid] = sum;
    }
}

// ---------- Kernel 3: heads (3 scales + g-row) + final MLP ----------
__global__ __launch_bounds__(256) void k_mlp(const float* __restrict__ pooled,
                                             const float* __restrict__ gpart,
                                             const float* __restrict__ W1, const float* __restrict__ b1,
                                             const float* __restrict__ W2, const float* __restrict__ b2,
                                             const float* __restrict__ P1, const float* __restrict__ bp1,
                                             const float* __restrict__ P2, const float* __restrict__ bp2,
                                             float* __restrict__ out, int n) {
    __shared__ float inp[26][64];     // 25 input rows + zero row
    __shared__ float h1[28][128];     // stage1 out; rows 0..7 reused as stage3 out
    __shared__ float catf[8][256];
    int tid = threadIdx.x;
    int box0 = blockIdx.x * 8;

    #pragma unroll
    for (int it = 0; it < 6; ++it) {
        int idx = tid + it * 256;          // < 1536 = 24*64
        int m = idx >> 6, c = idx & 63;
        int rb = m & 7, sc = m >> 3;
        inp[m][c] = (box0 + rb < n) ? pooled[(size_t)(box0 + rb) * 192 + sc * 64 + c] : 0.0f;
    }
    if (tid < 64) {
        inp[24][tid] = gpart[tid] * (1.0f / (float)(FH * FW));
        inp[25][tid] = 0.0f;
    }
    ((float*)h1)[26 * 128 + tid] = 0.0f;   // zero pad rows 26,27
    __syncthreads();

    // ---- Stage 1: h1[m][j] = relu(inp[m] @ W1 + b1), m in 0..25 ----
    {
        int j = tid & 127, grp = tid >> 7;
        int m0 = grp * 13;
        float acc[13];
        #pragma unroll
        for (int r = 0; r < 13; ++r) acc[r] = 0.0f;
        for (int c = 0; c < 64; c += 4) {
            float w0 = W1[(c    ) * 128 + j];
            float w1 = W1[(c + 1) * 128 + j];
            float w2 = W1[(c + 2) * 128 + j];
            float w3 = W1[(c + 3) * 128 + j];
            #pragma unroll
            for (int r = 0; r < 13; ++r) {
                float4 x = *(const float4*)&inp[m0 + r][c];
                acc[r] = fmaf(x.x, w0, fmaf(x.y, w1, fmaf(x.z, w2, fmaf(x.w, w3, acc[r]))));
            }
        }
        float bb = b1[j];
        #pragma unroll
        for (int r = 0; r < 13; ++r) h1[m0 + r][j] = fmaxf(acc[r] + bb, 0.0f);
    }
    __syncthreads();

    // ---- Stage 2: h2[m][k] = relu(h1[m] @ W2 + b2) -> catf / hg ----
    {
        int k = tid & 63, q = tid >> 6;
        int m0 = q * 7;
        float acc[7];
        #pragma unroll
        for (int r = 0; r < 7; ++r) acc[r] = 0.0f;
        for (int jj = 0; jj < 128; jj += 4) {
            float w0 = W2[(jj    ) * 64 + k];
            float w1 = W2[(jj + 1) * 64 + k];
            float w2 = W2[(jj + 2) * 64 + k];
            float w3 = W2[(jj + 3) * 64 + k];
            #pragma unroll
            for (int r = 0; r < 7; ++r) {
                float4 x = *(const float4*)&h1[m0 + r][jj];
                acc[r] = fmaf(x.x, w0, fmaf(x.y, w1, fmaf(x.z, w2, fmaf(x.w, w3, acc[r]))));
            }
        }
        float bb = b2[k];
        #pragma unroll
        for (int r = 0; r < 7; ++r) {
            int m = m0 + r;
            float v = fmaxf(acc[r] + bb, 0.0f);
            if (m < 24) {
                catf[m & 7][(m >> 3) * 64 + k] = v;
            } else if (m == 24) {
                #pragma unroll
                for (int rr = 0; rr < 8; ++rr) catf[rr][192 + k] = v;
            }
        }
    }
    __syncthreads();

    // ---- Stage 3: hid[r][j] = relu(catf[r] @ P1 + bp1) -> h1 rows 0..7 ----
    {
        int j = tid & 127, grp = tid >> 7;
        int r0 = grp * 4;
        float acc[4] = {0.0f, 0.0f, 0.0f, 0.0f};
        for (int c = 0; c < 256; c += 4) {
            float w0 = P1[(c    ) * 128 + j];
            float w1 = P1[(c + 1) * 128 + j];
            float w2 = P1[(c + 2) * 128 + j];
            float w3 = P1[(c + 3) * 128 + j];
            #pragma unroll
            for (int r = 0; r < 4; ++r) {
                float4 x = *(const float4*)&catf[r0 + r][c];
                acc[r] = fmaf(x.x, w0, fmaf(x.y, w1, fmaf(x.z, w2, fmaf(x.w, w3, acc[r]))));
            }
        }
        float bb = bp1[j];
        #pragma unroll
        for (int r = 0; r < 4; ++r) h1[r0 + r][j] = fmaxf(acc[r] + bb, 0.0f);
    }
    __syncthreads();

    // ---- Stage 4: out[r][k] = relu(hid[r] @ P2 + bp2) ----
    {
        int k = tid & 63, q = tid >> 6;
        int r0 = q * 2;
        float acc[2] = {0.0f, 0.0f};
        for (int jj = 0; jj < 128; jj += 4) {
            float w0 = P2[(jj    ) * 64 + k];
            float w1 = P2[(jj + 1) * 64 + k];
            float w2 = P2[(jj + 2) * 64 + k];
            float w3 = P2[(jj + 3) * 64 + k];
            #pragma unroll
            for (int r = 0; r < 2; ++r) {
                float4 x = *(const float4*)&h1[r0 + r][jj];
                acc[r] = fmaf(x.x, w0, fmaf(x.y, w1, fmaf(x.z, w2, fmaf(x.w, w3, acc[r]))));
            }
        }
        float bb = bp2[k];
        #pragma unroll
        for (int r = 0; r < 2; ++r) {
            int row = box0 + r0 + r;
            if (row < n) out[(size_t)row * 64 + k] = fmaxf(acc[r] + bb, 0.0f);
        }
    }
}

extern "C" void kernel_launch(void* const* d_in, const int* in_sizes, int n_in,
                              void* d_out, int out_size, void* d_ws, size_t ws_size,
                              hipStream_t stream) {
    const float* fm    = (const float*)d_in[0];
    const float* boxes = (const float*)d_in[1];
    const float* W1    = (const float*)d_in[2];
    const float* b1    = (const float*)d_in[3];
    const float* W2    = (const float*)d_in[4];
    const float* b2    = (const float*)d_in[5];
    const float* P1    = (const float*)d_in[6];
    const float* bp1   = (const float*)d_in[7];
    const float* P2    = (const float*)d_in[8];
    const float* bp2   = (const float*)d_in[9];
    float* ws = (float*)d_ws;
    __half* fmT   = (__half*)(ws + WS_FMT);
    float* gpart  = ws + WS_GP;
    float* pooled = ws + WS_POOL;
    float* out = (float*)d_out;
    int n = in_sizes[1] / 4;   // 4000 boxes

    hipMemsetAsync(gpart, 0, 64 * sizeof(float), stream);
    k_transpose<<<dim3(4, 240), 256, 0, stream>>>(fm, fmT, gpart);
    k_pool<<<n, 256, 0, stream>>>(fmT, boxes, pooled);
    k_mlp<<<(n + 7) / 8, 256, 0, stream>>>(pooled, gpart, W1, b1, W2, b2,
                                           P1, bp1, P2, bp2, out, n);
}

// Round 5
// 151.769 us; speedup vs baseline: 2.0743x; 1.1168x over previous
//
#include <hip/hip_runtime.h>
#include <hip/hip_fp16.h>

#define FH 240
#define FW 240
constexpr float IMG = 960.0f;

// ---------------- ws layout (floats) ----------------
static constexpr int WS_FMT  = 0;          // fmT fp16 [240][240][64] = 1,843,200 floats
static constexpr int WS_GP   = 3686400;    // gpart [64] (atomic-accumulated)
static constexpr int WS_POOL = 3686656;    // pooled [N][192]

// ---------- Kernel 1: transpose fm [C,H,W] -> fp16 fmT [H,W,C], + channel sums ----------
__global__ __launch_bounds__(256) void k_transpose(const float* __restrict__ fm,
                                                   __half* __restrict__ fmT,
                                                   float* __restrict__ gpart) {
    __shared__ float tile[64][65];
    int y  = blockIdx.y;
    int x0 = blockIdx.x * 64;
    int tid = threadIdx.x;
    int lane = tid & 63;
    int wv   = tid >> 6;
    int x = x0 + lane;
    bool xin = (x < FW);
    #pragma unroll
    for (int k = 0; k < 16; ++k) {
        int c = wv + k * 4;
        tile[c][lane] = xin ? fm[c * (FH * FW) + y * FW + x] : 0.0f;
    }
    __syncthreads();

    if (tid < 64) {
        float s = 0.0f;
        #pragma unroll
        for (int i = 0; i < 64; ++i) s += tile[tid][i];
        atomicAdd(gpart + tid, s);
    }

    #pragma unroll
    for (int it = 0; it < 2; ++it) {
        int idx = tid + it * 256;       // 0..511
        int xl  = idx >> 3;             // 0..63
        int co  = (idx & 7) * 8;        // 0,8,...,56
        int xx  = x0 + xl;
        if (xx < FW) {
            union { float4 f4; __half2 h2[4]; } u;
            #pragma unroll
            for (int i = 0; i < 4; ++i)
                u.h2[i] = __floats2half2_rn(tile[co + 2*i][xl], tile[co + 2*i + 1][xl]);
            *(float4*)&fmT[((size_t)(y * FW + xx)) * 64 + co] = u.f4;
        }
    }
}

// ---------- Kernel 2: ROI bilinear pooling (two-phase, fp16 gathers) ----------
#define NSAMP 179   // 9 + 49 + 121

__device__ __forceinline__ void acc8(float* a, const __half* __restrict__ base,
                                     int off, int c8, float w) {
    float4 raw = *(const float4*)(base + off + c8);   // 8 fp16
    const __half2* h = (const __half2*)&raw;
    #pragma unroll
    for (int i = 0; i < 4; ++i) {
        float2 f = __half22float2(h[i]);
        a[2*i]     = fmaf(w, f.x, a[2*i]);
        a[2*i + 1] = fmaf(w, f.y, a[2*i + 1]);
    }
}

__global__ __launch_bounds__(256) void k_pool(const __half* __restrict__ fmT,
                                              const float* __restrict__ boxes,
                                              float* __restrict__ pooled) {
    __shared__ int   smp[NSAMP * 8];
    __shared__ float part[3][64 * 33];

    int box = blockIdx.x;
    int tid = threadIdx.x;

    if (tid < NSAMP) {
        float bx1 = boxes[box * 4 + 0], by1 = boxes[box * 4 + 1];
        float bx2 = boxes[box * 4 + 2], by2 = boxes[box * 4 + 3];
        float x1n = (bx1 / IMG) * 2.0f - 1.0f;
        float y1n = (by1 / IMG) * 2.0f - 1.0f;
        float x2n = (bx2 / IMG) * 2.0f - 1.0f;
        float y2n = (by2 / IMG) * 2.0f - 1.0f;
        float cx = (x1n + x2n) * 0.5f, cy = (y1n + y2n) * 0.5f;
        float w2 = fmaxf(x2n - x1n, 1e-6f) * 0.5f;
        float h2 = fmaxf(y2n - y1n, 1e-6f) * 0.5f;

        int S, s;
        if (tid < 9)       { S = 3;  s = tid; }
        else if (tid < 58) { S = 7;  s = tid - 9; }
        else               { S = 11; s = tid - 58; }
        int i = s / S;
        int j = s - i * S;
        float Sf = (float)S;
        float bj = (2.0f * (float)j + 1.0f) / Sf - 1.0f;
        float bi = (2.0f * (float)i + 1.0f) / Sf - 1.0f;
        float gx = w2 * bj + cx;
        float gy = h2 * bi + cy;
        float ix = ((gx + 1.0f) * 240.0f - 1.0f) * 0.5f;
        float iy = ((gy + 1.0f) * 240.0f - 1.0f) * 0.5f;
        float x0f = floorf(ix), y0f = floorf(iy);
        float dx = ix - x0f,    dy = iy - y0f;
        int x0 = (int)x0f, y0 = (int)y0f;
        int x1 = x0 + 1,   y1 = y0 + 1;
        float inv = 1.0f / (Sf * Sf);
        float wx0 = (x0 >= 0 && x0 < FW) ? (1.0f - dx) : 0.0f;
        float wx1 = (x1 >= 0 && x1 < FW) ? dx          : 0.0f;
        float wy0 = (y0 >= 0 && y0 < FH) ? (1.0f - dy) : 0.0f;
        float wy1 = (y1 >= 0 && y1 < FH) ? dy          : 0.0f;
        int x0c = min(max(x0, 0), FW - 1), x1c = min(max(x1, 0), FW - 1);
        int y0c = min(max(y0, 0), FH - 1), y1c = min(max(y1, 0), FH - 1);
        int r0 = y0c * FW, r1 = y1c * FW;
        smp[tid * 8 + 0] = (r0 + x0c) * 64;
        smp[tid * 8 + 1] = (r0 + x1c) * 64;
        smp[tid * 8 + 2] = (r1 + x0c) * 64;
        smp[tid * 8 + 3] = (r1 + x1c) * 64;
        float* wp = (float*)&smp[tid * 8 + 4];
        wp[0] = wx0 * wy0 * inv;
        wp[1] = wx1 * wy0 * inv;
        wp[2] = wx0 * wy1 * inv;
        wp[3] = wx1 * wy1 * inv;
    }
    __syncthreads();

    int slot = tid >> 3;
    int l    = tid & 7;
    int c8   = l << 3;

    float a[3][8];
    #pragma unroll
    for (int sc = 0; sc < 3; ++sc)
        #pragma unroll
        for (int k = 0; k < 8; ++k) a[sc][k] = 0.0f;

    const int start[3] = {0, 9, 58};
    const int end_[3]  = {9, 58, NSAMP};
    #pragma unroll
    for (int sc = 0; sc < 3; ++sc) {
        for (int s = start[sc] + slot; s < end_[sc]; s += 32) {
            int4   bo = *(const int4*)  &smp[s * 8];
            float4 wv = *(const float4*)&smp[s * 8 + 4];
            acc8(a[sc], fmT, bo.x, c8, wv.x);
            acc8(a[sc], fmT, bo.y, c8, wv.y);
            acc8(a[sc], fmT, bo.z, c8, wv.z);
            acc8(a[sc], fmT, bo.w, c8, wv.w);
        }
    }
    #pragma unroll
    for (int sc = 0; sc < 3; ++sc)
        #pragma unroll
        for (int i = 0; i < 8; ++i)
            part[sc][(c8 + i) * 33 + slot] = a[sc][i];
    __syncthreads();

    if (tid < 192) {
        int sc = tid >> 6, c = tid & 63;
        float sum = 0.0f;
        #pragma unroll
        for (int q = 0; q < 32; ++q) sum += part[sc][c * 33 + q];
        pooled[(size_t)box * 192 + tid] = sum;
    }
}

// ---------- Kernel 3: heads + final MLP, 4x4 register-tiled micro-GEMM ----------
// 8 boxes/block -> 24 head rows + g row, padded to M=32.
// Stage1: [32x64]@[64x128]; Stage2: [32x128]@[128x64] (K split 2);
// Stage3: [8x256]@[256x128] (K split 4); Stage4: [8x128]@[128x64] (K split 4).
__global__ __launch_bounds__(256) void k_mlp(const float* __restrict__ pooled,
                                             const float* __restrict__ gpart,
                                             const float* __restrict__ W1, const float* __restrict__ b1,
                                             const float* __restrict__ W2, const float* __restrict__ b2,
                                             const float* __restrict__ P1, const float* __restrict__ bp1,
                                             const float* __restrict__ P2, const float* __restrict__ bp2,
                                             float* __restrict__ out, int n) {
    __shared__ float inp[32][64];        // 8 KB
    __shared__ float h1[32][132];        // 16.9 KB (pad 132 breaks row-bank aliasing)
    __shared__ float h2p[2][32][64];     // 16 KB
    __shared__ float catf[8][256];       // 8 KB
    __shared__ float hidp[4][8][128];    // 16 KB
    __shared__ float outp[4][8][64];     // 8 KB
    int tid = threadIdx.x;
    int box0 = blockIdx.x * 8;

    // ---- load inputs: rows 0..23 pooled, 24 = g, 25..31 = 0 ----
    #pragma unroll
    for (int it = 0; it < 6; ++it) {
        int idx = tid + it * 256;          // < 1536
        int m = idx >> 6, c = idx & 63;
        int rb = m & 7, sc = m >> 3;
        inp[m][c] = (box0 + rb < n) ? pooled[(size_t)(box0 + rb) * 192 + sc * 64 + c] : 0.0f;
    }
    #pragma unroll
    for (int it = 0; it < 2; ++it) {
        int idx = tid + it * 256;          // < 512
        int m = 24 + (idx >> 6), c = idx & 63;
        inp[m][c] = (m == 24) ? gpart[c] * (1.0f / 57600.0f) : 0.0f;
    }
    __syncthreads();

    // ---- Stage 1: h1 = relu(inp @ W1 + b1) ----
    {
        int cg = tid & 31, rg = tid >> 5;
        int c4 = cg * 4, r4 = rg * 4;
        float acc[4][4] = {};
        for (int k = 0; k < 64; k += 4) {
            float4 a[4];
            #pragma unroll
            for (int rr = 0; rr < 4; ++rr) a[rr] = *(const float4*)&inp[r4 + rr][k];
            #pragma unroll
            for (int kk = 0; kk < 4; ++kk) {
                float4 w = *(const float4*)&W1[(k + kk) * 128 + c4];
                #pragma unroll
                for (int rr = 0; rr < 4; ++rr) {
                    float av = ((const float*)&a[rr])[kk];
                    acc[rr][0] = fmaf(av, w.x, acc[rr][0]);
                    acc[rr][1] = fmaf(av, w.y, acc[rr][1]);
                    acc[rr][2] = fmaf(av, w.z, acc[rr][2]);
                    acc[rr][3] = fmaf(av, w.w, acc[rr][3]);
                }
            }
        }
        float4 bb = *(const float4*)&b1[c4];
        #pragma unroll
        for (int rr = 0; rr < 4; ++rr) {
            float4 o;
            o.x = fmaxf(acc[rr][0] + bb.x, 0.0f);
            o.y = fmaxf(acc[rr][1] + bb.y, 0.0f);
            o.z = fmaxf(acc[rr][2] + bb.z, 0.0f);
            o.w = fmaxf(acc[rr][3] + bb.w, 0.0f);
            *(float4*)&h1[r4 + rr][c4] = o;
        }
    }
    __syncthreads();

    // ---- Stage 2: h2p[kg] = inp-rows @ W2 partials (K split 2) ----
    {
        int cg = tid & 15, rg = (tid >> 4) & 7, kg = tid >> 7;
        int c4 = cg * 4, r4 = rg * 4, k0 = kg * 64;
        float acc[4][4] = {};
        for (int k = k0; k < k0 + 64; k += 4) {
            float4 a[4];
            #pragma unroll
            for (int rr = 0; rr < 4; ++rr) a[rr] = *(const float4*)&h1[r4 + rr][k];
            #pragma unroll
            for (int kk = 0; kk < 4; ++kk) {
                float4 w = *(const float4*)&W2[(k + kk) * 64 + c4];
                #pragma unroll
                for (int rr = 0; rr < 4; ++rr) {
                    float av = ((const float*)&a[rr])[kk];
                    acc[rr][0] = fmaf(av, w.x, acc[rr][0]);
                    acc[rr][1] = fmaf(av, w.y, acc[rr][1]);
                    acc[rr][2] = fmaf(av, w.z, acc[rr][2]);
                    acc[rr][3] = fmaf(av, w.w, acc[rr][3]);
                }
            }
        }
        #pragma unroll
        for (int rr = 0; rr < 4; ++rr)
            *(float4*)&h2p[kg][r4 + rr][c4] = make_float4(acc[rr][0], acc[rr][1], acc[rr][2], acc[rr][3]);
    }
    __syncthreads();
    // merge -> catf (scatter; rows 25..31 discarded)
    #pragma unroll
    for (int it = 0; it < 8; ++it) {
        int idx = tid + it * 256;          // < 2048
        int r = idx >> 6, c = idx & 63;
        float v = fmaxf(h2p[0][r][c] + h2p[1][r][c] + b2[c], 0.0f);
        if (r < 24) {
            catf[r & 7][(r >> 3) * 64 + c] = v;
        } else if (r == 24) {
            #pragma unroll
            for (int rr = 0; rr < 8; ++rr) catf[rr][192 + c] = v;
        }
    }
    __syncthreads();

    // ---- Stage 3: hidp[kg] = catf @ P1 partials (K split 4) ----
    {
        int cg = tid & 31, rg = (tid >> 5) & 1, kg = tid >> 6;
        int c4 = cg * 4, r4 = rg * 4, k0 = kg * 64;
        float acc[4][4] = {};
        for (int k = k0; k < k0 + 64; k += 4) {
            float4 a[4];
            #pragma unroll
            for (int rr = 0; rr < 4; ++rr) a[rr] = *(const float4*)&catf[r4 + rr][k];
            #pragma unroll
            for (int kk = 0; kk < 4; ++kk) {
                float4 w = *(const float4*)&P1[(k + kk) * 128 + c4];
                #pragma unroll
                for (int rr = 0; rr < 4; ++rr) {
                    float av = ((const float*)&a[rr])[kk];
                    acc[rr][0] = fmaf(av, w.x, acc[rr][0]);
                    acc[rr][1] = fmaf(av, w.y, acc[rr][1]);
                    acc[rr][2] = fmaf(av, w.z, acc[rr][2]);
                    acc[rr][3] = fmaf(av, w.w, acc[rr][3]);
                }
            }
        }
        #pragma unroll
        for (int rr = 0; rr < 4; ++rr)
            *(float4*)&hidp[kg][r4 + rr][c4] = make_float4(acc[rr][0], acc[rr][1], acc[rr][2], acc[rr][3]);
    }
    __syncthreads();
    // merge -> hid (reuse h1 rows 0..7)
    #pragma unroll
    for (int it = 0; it < 4; ++it) {
        int idx = tid + it * 256;          // < 1024
        int r = idx >> 7, j = idx & 127;
        h1[r][j] = fmaxf(hidp[0][r][j] + hidp[1][r][j] + hidp[2][r][j] + hidp[3][r][j] + bp1[j], 0.0f);
    }
    __syncthreads();

    // ---- Stage 4: outp[kg] = hid @ P2 partials (K split 4, 128 threads) ----
    if (tid < 128) {
        int cg = tid & 15, rg = (tid >> 4) & 1, kg = tid >> 5;
        int c4 = cg * 4, r4 = rg * 4, k0 = kg * 32;
        float acc[4][4] = {};
        for (int k = k0; k < k0 + 32; k += 4) {
            float4 a[4];
            #pragma unroll
            for (int rr = 0; rr < 4; ++rr) a[rr] = *(const float4*)&h1[r4 + rr][k];
            #pragma unroll
            for (int kk = 0; kk < 4; ++kk) {
                float4 w = *(const float4*)&P2[(k + kk) * 64 + c4];
                #pragma unroll
                for (int rr = 0; rr < 4; ++rr) {
                    float av = ((const float*)&a[rr])[kk];
                    acc[rr][0] = fmaf(av, w.x, acc[rr][0]);
                    acc[rr][1] = fmaf(av, w.y, acc[rr][1]);
                    acc[rr][2] = fmaf(av, w.z, acc[rr][2]);
                    acc[rr][3] = fmaf(av, w.w, acc[rr][3]);
                }
            }
        }
        #pragma unroll
        for (int rr = 0; rr < 4; ++rr)
            *(float4*)&outp[kg][r4 + rr][c4] = make_float4(acc[rr][0], acc[rr][1], acc[rr][2], acc[rr][3]);
    }
    __syncthreads();
    // final merge + store
    #pragma unroll
    for (int it = 0; it < 2; ++it) {
        int idx = tid + it * 256;          // < 512
        int r = idx >> 6, c = idx & 63;
        int row = box0 + r;
        if (row < n) {
            float v = fmaxf(outp[0][r][c] + outp[1][r][c] + outp[2][r][c] + outp[3][r][c] + bp2[c], 0.0f);
            out[(size_t)row * 64 + c] = v;
        }
    }
}

extern "C" void kernel_launch(void* const* d_in, const int* in_sizes, int n_in,
                              void* d_out, int out_size, void* d_ws, size_t ws_size,
                              hipStream_t stream) {
    const float* fm    = (const float*)d_in[0];
    const float* boxes = (const float*)d_in[1];
    const float* W1    = (const float*)d_in[2];
    const float* b1    = (const float*)d_in[3];
    const float* W2    = (const float*)d_in[4];
    const float* b2    = (const float*)d_in[5];
    const float* P1    = (const float*)d_in[6];
    const float* bp1   = (const float*)d_in[7];
    const float* P2    = (const float*)d_in[8];
    const float* bp2   = (const float*)d_in[9];
    float* ws = (float*)d_ws;
    __half* fmT   = (__half*)(ws + WS_FMT);
    float* gpart  = ws + WS_GP;
    float* pooled = ws + WS_POOL;
    float* out = (float*)d_out;
    int n = in_sizes[1] / 4;   // 4000 boxes

    hipMemsetAsync(gpart, 0, 64 * sizeof(float), stream);
    k_transpose<<<dim3(4, 240), 256, 0, stream>>>(fm, fmT, gpart);
    k_pool<<<n, 256, 0, stream>>>(fmT, boxes, pooled);
    k_mlp<<<(n + 7) / 8, 256, 0, stream>>>(pooled, gpart, W1, b1, W2, b2,
                                           P1, bp1, P2, bp2, out, n);
}

// Round 6
// 130.226 us; speedup vs baseline: 2.4174x; 1.1654x over previous
//
#include <hip/hip_runtime.h>
#include <hip/hip_fp16.h>

#define FH 240
#define FW 240
constexpr float IMG = 960.0f;

// ---------------- ws layout (floats) ----------------
static constexpr int WS_FMT   = 0;        // fmT fp16 [240][240][64] -> 1,843,200 float slots
static constexpr int WS_GPART = 1843200;  // gpartial [960][64]
static constexpr int WS_G     = 1904640;  // g [64] (pre-scaled by 1/57600)
static constexpr int WS_PERM  = 1904704;  // perm [4000] ints
static constexpr int WS_POOL  = 1908736;  // pooled [N][192]

// ---------- Kernel 1: blocks 0..959 transpose fm -> fp16 fmT + channel partials;
//                      block 960: counting-sort boxes by center-y -> perm ----------
__global__ __launch_bounds__(256) void k_prep(const float* __restrict__ fm,
                                              __half* __restrict__ fmT,
                                              float* __restrict__ gpartial,
                                              const float* __restrict__ boxes,
                                              int* __restrict__ perm, int n) {
    __shared__ float tile[64][65];
    __shared__ int hist[256];
    __shared__ int offs[256];
    int bid = blockIdx.x;
    int tid = threadIdx.x;

    if (bid < 960) {
        int y  = bid >> 2;
        int x0 = (bid & 3) * 64;
        int lane = tid & 63;
        int wv   = tid >> 6;
        int x = x0 + lane;
        bool xin = (x < FW);
        #pragma unroll
        for (int k = 0; k < 16; ++k) {
            int c = wv + k * 4;
            tile[c][lane] = xin ? fm[c * (FH * FW) + y * FW + x] : 0.0f;
        }
        __syncthreads();

        // per-block channel partial sums (pad lanes are zero)
        if (tid < 64) {
            float s = 0.0f;
            #pragma unroll
            for (int i = 0; i < 64; ++i) s += tile[tid][i];
            gpartial[bid * 64 + tid] = s;
        }

        // write fp16, 8 channels per thread (16 B stores)
        #pragma unroll
        for (int it = 0; it < 2; ++it) {
            int idx = tid + it * 256;       // 0..511
            int xl  = idx >> 3;             // 0..63
            int co  = (idx & 7) * 8;        // 0,8,...,56
            int xx  = x0 + xl;
            if (xx < FW) {
                union { float4 f4; __half2 h2[4]; } u;
                #pragma unroll
                for (int i = 0; i < 4; ++i)
                    u.h2[i] = __floats2half2_rn(tile[co + 2*i][xl], tile[co + 2*i + 1][xl]);
                *(float4*)&fmT[((size_t)(y * FW + xx)) * 64 + co] = u.f4;
            }
        }
    } else {
        // ---- counting sort of boxes by quantized center-y ----
        hist[tid] = 0;
        __syncthreads();
        for (int i = tid; i < n; i += 256) {
            float cy = (boxes[i * 4 + 1] + boxes[i * 4 + 3]) * 0.5f;   // 0..960
            int b = min(255, max(0, (int)(cy * (256.0f / 960.0f))));
            atomicAdd(&hist[b], 1);
        }
        __syncthreads();
        offs[tid] = hist[tid];
        __syncthreads();
        for (int st = 1; st < 256; st <<= 1) {
            int t = (tid >= st) ? offs[tid - st] : 0;
            __syncthreads();
            offs[tid] += t;
            __syncthreads();
        }
        hist[tid] = offs[tid] - hist[tid];     // exclusive start per bucket
        __syncthreads();
        for (int i = tid; i < n; i += 256) {
            float cy = (boxes[i * 4 + 1] + boxes[i * 4 + 3]) * 0.5f;
            int b = min(255, max(0, (int)(cy * (256.0f / 960.0f))));
            int pos = atomicAdd(&hist[b], 1);
            perm[pos] = i;
        }
    }
}

// ---------- Kernel 2: ROI bilinear pooling (two-phase, fp16 gathers, sorted order) ----------
#define NSAMP 179   // 9 + 49 + 121

__device__ __forceinline__ void acc8(float* a, const __half* __restrict__ base,
                                     int off, int c8, float w) {
    float4 raw = *(const float4*)(base + off + c8);   // 8 fp16
    const __half2* h = (const __half2*)&raw;
    #pragma unroll
    for (int i = 0; i < 4; ++i) {
        float2 f = __half22float2(h[i]);
        a[2*i]     = fmaf(w, f.x, a[2*i]);
        a[2*i + 1] = fmaf(w, f.y, a[2*i + 1]);
    }
}

__global__ __launch_bounds__(256) void k_pool(const __half* __restrict__ fmT,
                                              const float* __restrict__ boxes,
                                              const int* __restrict__ perm,
                                              const float* __restrict__ gpartial,
                                              float* __restrict__ g,
                                              float* __restrict__ pooled) {
    __shared__ int   smp[NSAMP * 8];
    __shared__ float part[3][64 * 33];

    int tid = threadIdx.x;

    // block 0 extra duty: reduce gpartial -> g (pre-scaled)
    if (blockIdx.x == 0) {
        int c = tid & 63, q = tid >> 6;
        float s = 0.0f;
        for (int i = q * 240; i < q * 240 + 240; ++i) s += gpartial[i * 64 + c];
        ((float*)part)[tid] = s;
        __syncthreads();
        if (tid < 64) {
            float* p = (float*)part;
            g[tid] = (p[tid] + p[64 + tid] + p[128 + tid] + p[192 + tid]) * (1.0f / 57600.0f);
        }
        __syncthreads();
    }

    int box = perm[blockIdx.x];

    // --- Phase 1: one thread per sample ---
    if (tid < NSAMP) {
        float bx1 = boxes[box * 4 + 0], by1 = boxes[box * 4 + 1];
        float bx2 = boxes[box * 4 + 2], by2 = boxes[box * 4 + 3];
        float x1n = (bx1 / IMG) * 2.0f - 1.0f;
        float y1n = (by1 / IMG) * 2.0f - 1.0f;
        float x2n = (bx2 / IMG) * 2.0f - 1.0f;
        float y2n = (by2 / IMG) * 2.0f - 1.0f;
        float cx = (x1n + x2n) * 0.5f, cy = (y1n + y2n) * 0.5f;
        float w2 = fmaxf(x2n - x1n, 1e-6f) * 0.5f;
        float h2 = fmaxf(y2n - y1n, 1e-6f) * 0.5f;

        int S, s;
        if (tid < 9)       { S = 3;  s = tid; }
        else if (tid < 58) { S = 7;  s = tid - 9; }
        else               { S = 11; s = tid - 58; }
        int i = s / S;
        int j = s - i * S;
        float Sf = (float)S;
        float bj = (2.0f * (float)j + 1.0f) / Sf - 1.0f;
        float bi = (2.0f * (float)i + 1.0f) / Sf - 1.0f;
        float gx = w2 * bj + cx;
        float gy = h2 * bi + cy;
        float ix = ((gx + 1.0f) * 240.0f - 1.0f) * 0.5f;
        float iy = ((gy + 1.0f) * 240.0f - 1.0f) * 0.5f;
        float x0f = floorf(ix), y0f = floorf(iy);
        float dx = ix - x0f,    dy = iy - y0f;
        int x0 = (int)x0f, y0 = (int)y0f;
        int x1 = x0 + 1,   y1 = y0 + 1;
        float inv = 1.0f / (Sf * Sf);
        float wx0 = (x0 >= 0 && x0 < FW) ? (1.0f - dx) : 0.0f;
        float wx1 = (x1 >= 0 && x1 < FW) ? dx          : 0.0f;
        float wy0 = (y0 >= 0 && y0 < FH) ? (1.0f - dy) : 0.0f;
        float wy1 = (y1 >= 0 && y1 < FH) ? dy          : 0.0f;
        int x0c = min(max(x0, 0), FW - 1), x1c = min(max(x1, 0), FW - 1);
        int y0c = min(max(y0, 0), FH - 1), y1c = min(max(y1, 0), FH - 1);
        int r0 = y0c * FW, r1 = y1c * FW;
        smp[tid * 8 + 0] = (r0 + x0c) * 64;
        smp[tid * 8 + 1] = (r0 + x1c) * 64;
        smp[tid * 8 + 2] = (r1 + x0c) * 64;
        smp[tid * 8 + 3] = (r1 + x1c) * 64;
        float* wp = (float*)&smp[tid * 8 + 4];
        wp[0] = wx0 * wy0 * inv;
        wp[1] = wx1 * wy0 * inv;
        wp[2] = wx0 * wy1 * inv;
        wp[3] = wx1 * wy1 * inv;
    }
    __syncthreads();

    // --- Phase 2: 32 slots x 8 lanes, 8 channels/lane, fp16 16-B gathers ---
    int slot = tid >> 3;
    int l    = tid & 7;
    int c8   = l << 3;

    float a[3][8];
    #pragma unroll
    for (int sc = 0; sc < 3; ++sc)
        #pragma unroll
        for (int k = 0; k < 8; ++k) a[sc][k] = 0.0f;

    const int start[3] = {0, 9, 58};
    const int end_[3]  = {9, 58, NSAMP};
    #pragma unroll
    for (int sc = 0; sc < 3; ++sc) {
        for (int s = start[sc] + slot; s < end_[sc]; s += 32) {
            int4   bo = *(const int4*)  &smp[s * 8];
            float4 wv = *(const float4*)&smp[s * 8 + 4];
            acc8(a[sc], fmT, bo.x, c8, wv.x);
            acc8(a[sc], fmT, bo.y, c8, wv.y);
            acc8(a[sc], fmT, bo.z, c8, wv.z);
            acc8(a[sc], fmT, bo.w, c8, wv.w);
        }
    }
    #pragma unroll
    for (int sc = 0; sc < 3; ++sc)
        #pragma unroll
        for (int i = 0; i < 8; ++i)
            part[sc][(c8 + i) * 33 + slot] = a[sc][i];
    __syncthreads();

    if (tid < 192) {
        int sc = tid >> 6, c = tid & 63;
        float sum = 0.0f;
        #pragma unroll
        for (int q = 0; q < 32; ++q) sum += part[sc][c * 33 + q];
        pooled[(size_t)box * 192 + tid] = sum;
    }
}

// ---------- Kernel 3: heads + final MLP, 4x4 register-tiled micro-GEMM ----------
__global__ __launch_bounds__(256) void k_mlp(const float* __restrict__ pooled,
                                             const float* __restrict__ g,
                                             const float* __restrict__ W1, const float* __restrict__ b1,
                                             const float* __restrict__ W2, const float* __restrict__ b2,
                                             const float* __restrict__ P1, const float* __restrict__ bp1,
                                             const float* __restrict__ P2, const float* __restrict__ bp2,
                                             float* __restrict__ out, int n) {
    __shared__ float inp[32][64];
    __shared__ float h1[32][132];
    __shared__ float h2p[2][32][64];
    __shared__ float catf[8][256];
    __shared__ float hidp[4][8][128];
    __shared__ float outp[4][8][64];
    int tid = threadIdx.x;
    int box0 = blockIdx.x * 8;

    #pragma unroll
    for (int it = 0; it < 6; ++it) {
        int idx = tid + it * 256;          // < 1536
        int m = idx >> 6, c = idx & 63;
        int rb = m & 7, sc = m >> 3;
        inp[m][c] = (box0 + rb < n) ? pooled[(size_t)(box0 + rb) * 192 + sc * 64 + c] : 0.0f;
    }
    #pragma unroll
    for (int it = 0; it < 2; ++it) {
        int idx = tid + it * 256;          // < 512
        int m = 24 + (idx >> 6), c = idx & 63;
        inp[m][c] = (m == 24) ? g[c] : 0.0f;
    }
    __syncthreads();

    // ---- Stage 1: h1 = relu(inp @ W1 + b1) ----
    {
        int cg = tid & 31, rg = tid >> 5;
        int c4 = cg * 4, r4 = rg * 4;
        float acc[4][4] = {};
        for (int k = 0; k < 64; k += 4) {
            float4 a[4];
            #pragma unroll
            for (int rr = 0; rr < 4; ++rr) a[rr] = *(const float4*)&inp[r4 + rr][k];
            #pragma unroll
            for (int kk = 0; kk < 4; ++kk) {
                float4 w = *(const float4*)&W1[(k + kk) * 128 + c4];
                #pragma unroll
                for (int rr = 0; rr < 4; ++rr) {
                    float av = ((const float*)&a[rr])[kk];
                    acc[rr][0] = fmaf(av, w.x, acc[rr][0]);
                    acc[rr][1] = fmaf(av, w.y, acc[rr][1]);
                    acc[rr][2] = fmaf(av, w.z, acc[rr][2]);
                    acc[rr][3] = fmaf(av, w.w, acc[rr][3]);
                }
            }
        }
        float4 bb = *(const float4*)&b1[c4];
        #pragma unroll
        for (int rr = 0; rr < 4; ++rr) {
            float4 o;
            o.x = fmaxf(acc[rr][0] + bb.x, 0.0f);
            o.y = fmaxf(acc[rr][1] + bb.y, 0.0f);
            o.z = fmaxf(acc[rr][2] + bb.z, 0.0f);
            o.w = fmaxf(acc[rr][3] + bb.w, 0.0f);
            *(float4*)&h1[r4 + rr][c4] = o;
        }
    }
    __syncthreads();

    // ---- Stage 2: h2p[kg] = h1 @ W2 partials (K split 2) ----
    {
        int cg = tid & 15, rg = (tid >> 4) & 7, kg = tid >> 7;
        int c4 = cg * 4, r4 = rg * 4, k0 = kg * 64;
        float acc[4][4] = {};
        for (int k = k0; k < k0 + 64; k += 4) {
            float4 a[4];
            #pragma unroll
            for (int rr = 0; rr < 4; ++rr) a[rr] = *(const float4*)&h1[r4 + rr][k];
            #pragma unroll
            for (int kk = 0; kk < 4; ++kk) {
                float4 w = *(const float4*)&W2[(k + kk) * 64 + c4];
                #pragma unroll
                for (int rr = 0; rr < 4; ++rr) {
                    float av = ((const float*)&a[rr])[kk];
                    acc[rr][0] = fmaf(av, w.x, acc[rr][0]);
                    acc[rr][1] = fmaf(av, w.y, acc[rr][1]);
                    acc[rr][2] = fmaf(av, w.z, acc[rr][2]);
                    acc[rr][3] = fmaf(av, w.w, acc[rr][3]);
                }
            }
        }
        #pragma unroll
        for (int rr = 0; rr < 4; ++rr)
            *(float4*)&h2p[kg][r4 + rr][c4] = make_float4(acc[rr][0], acc[rr][1], acc[rr][2], acc[rr][3]);
    }
    __syncthreads();
    #pragma unroll
    for (int it = 0; it < 8; ++it) {
        int idx = tid + it * 256;          // < 2048
        int r = idx >> 6, c = idx & 63;
        float v = fmaxf(h2p[0][r][c] + h2p[1][r][c] + b2[c], 0.0f);
        if (r < 24) {
            catf[r & 7][(r >> 3) * 64 + c] = v;
        } else if (r == 24) {
            #pragma unroll
            for (int rr = 0; rr < 8; ++rr) catf[rr][192 + c] = v;
        }
    }
    __syncthreads();

    // ---- Stage 3: hidp[kg] = catf @ P1 partials (K split 4) ----
    {
        int cg = tid & 31, rg = (tid >> 5) & 1, kg = tid >> 6;
        int c4 = cg * 4, r4 = rg * 4, k0 = kg * 64;
        float acc[4][4] = {};
        for (int k = k0; k < k0 + 64; k += 4) {
            float4 a[4];
            #pragma unroll
            for (int rr = 0; rr < 4; ++rr) a[rr] = *(const float4*)&catf[r4 + rr][k];
            #pragma unroll
            for (int kk = 0; kk < 4; ++kk) {
                float4 w = *(const float4*)&P1[(k + kk) * 128 + c4];
                #pragma unroll
                for (int rr = 0; rr < 4; ++rr) {
                    float av = ((const float*)&a[rr])[kk];
                    acc[rr][0] = fmaf(av, w.x, acc[rr][0]);
                    acc[rr][1] = fmaf(av, w.y, acc[rr][1]);
                    acc[rr][2] = fmaf(av, w.z, acc[rr][2]);
                    acc[rr][3] = fmaf(av, w.w, acc[rr][3]);
                }
            }
        }
        #pragma unroll
        for (int rr = 0; rr < 4; ++rr)
            *(float4*)&hidp[kg][r4 + rr][c4] = make_float4(acc[rr][0], acc[rr][1], acc[rr][2], acc[rr][3]);
    }
    __syncthreads();
    #pragma unroll
    for (int it = 0; it < 4; ++it) {
        int idx = tid + it * 256;          // < 1024
        int r = idx >> 7, j = idx & 127;
        h1[r][j] = fmaxf(hidp[0][r][j] + hidp[1][r][j] + hidp[2][r][j] + hidp[3][r][j] + bp1[j], 0.0f);
    }
    __syncthreads();

    // ---- Stage 4: outp[kg] = hid @ P2 partials (K split 4, 128 threads) ----
    if (tid < 128) {
        int cg = tid & 15, rg = (tid >> 4) & 1, kg = tid >> 5;
        int c4 = cg * 4, r4 = rg * 4, k0 = kg * 32;
        float acc[4][4] = {};
        for (int k = k0; k < k0 + 32; k += 4) {
            float4 a[4];
            #pragma unroll
            for (int rr = 0; rr < 4; ++rr) a[rr] = *(const float4*)&h1[r4 + rr][k];
            #pragma unroll
            for (int kk = 0; kk < 4; ++kk) {
                float4 w = *(const float4*)&P2[(k + kk) * 64 + c4];
                #pragma unroll
                for (int rr = 0; rr < 4; ++rr) {
                    float av = ((const float*)&a[rr])[kk];
                    acc[rr][0] = fmaf(av, w.x, acc[rr][0]);
                    acc[rr][1] = fmaf(av, w.y, acc[rr][1]);
                    acc[rr][2] = fmaf(av, w.z, acc[rr][2]);
                    acc[rr][3] = fmaf(av, w.w, acc[rr][3]);
                }
            }
        }
        #pragma unroll
        for (int rr = 0; rr < 4; ++rr)
            *(float4*)&outp[kg][r4 + rr][c4] = make_float4(acc[rr][0], acc[rr][1], acc[rr][2], acc[rr][3]);
    }
    __syncthreads();
    #pragma unroll
    for (int it = 0; it < 2; ++it) {
        int idx = tid + it * 256;          // < 512
        int r = idx >> 6, c = idx & 63;
        int row = box0 + r;
        if (row < n) {
            float v = fmaxf(outp[0][r][c] + outp[1][r][c] + outp[2][r][c] + outp[3][r][c] + bp2[c], 0.0f);
            out[(size_t)row * 64 + c] = v;
        }
    }
}

extern "C" void kernel_launch(void* const* d_in, const int* in_sizes, int n_in,
                              void* d_out, int out_size, void* d_ws, size_t ws_size,
                              hipStream_t stream) {
    const float* fm    = (const float*)d_in[0];
    const float* boxes = (const float*)d_in[1];
    const float* W1    = (const float*)d_in[2];
    const float* b1    = (const float*)d_in[3];
    const float* W2    = (const float*)d_in[4];
    const float* b2    = (const float*)d_in[5];
    const float* P1    = (const float*)d_in[6];
    const float* bp1   = (const float*)d_in[7];
    const float* P2    = (const float*)d_in[8];
    const float* bp2   = (const float*)d_in[9];
    float* ws = (float*)d_ws;
    __half* fmT    = (__half*)(ws + WS_FMT);
    float* gpartial = ws + WS_GPART;
    float* g        = ws + WS_G;
    int*   perm     = (int*)(ws + WS_PERM);
    float* pooled   = ws + WS_POOL;
    float* out = (float*)d_out;
    int n = in_sizes[1] / 4;   // 4000 boxes

    k_prep<<<961, 256, 0, stream>>>(fm, fmT, gpartial, boxes, perm, n);
    k_pool<<<n, 256, 0, stream>>>(fmT, boxes, perm, gpartial, g, pooled);
    k_mlp<<<(n + 7) / 8, 256, 0, stream>>>(pooled, g, W1, b1, W2, b2,
                                           P1, bp1, P2, bp2, out, n);
}